// Round 9
// baseline (1428.322 us; speedup 1.0000x reference)
//
#include <hip/hip_runtime.h>

// ---------------------------------------------------------------------------
// Atten2Map on MI355X (gfx950) — R7: two-kernel, occupancy-first
// shapes: nb=4 nloc=256 nnei=128 ni=128, ND=32 NH=8, NBL=1024
//
// Kd : detect nlist_mask dtype (int32 vs byte-packed)      -> flag in ws
// K0 : Wt[c][t] = W[t][c] * 32^-0.25, split bf16 hi/lo     -> ws (512 KB)
// KA : per-(b,l) GEMM g2@Wt (split-bf16, 3-MFMA), NO LDS / NO barriers,
//      g2 split in-register; writes bf16 slab [Q/K][h][row][d] to ws.
// KB : per-(b,l) attn: K frags resident, q in 16-row chunks,
//      S8[16][1153] f32 (72 KB -> 2 WG/CU, conflict-free), epilogue
//      *h2h2t -> h-contiguous 32B stores to out[b,l,q,k,h].
//
// R6 post-mortem: fused 150KB-LDS kernel = 1 WG/CU, 23% occupancy, all pipes
// idle (Mfma 4.7/VALU 23.6/HBM 14), 519 us. Occupancy > traffic here.
// R9: resubmit of R7 (rounds 7-8 lost to GPU acquisition timeouts).
// ---------------------------------------------------------------------------

typedef __attribute__((ext_vector_type(8))) short bf16x8;
typedef __attribute__((ext_vector_type(4))) float f32x4;

#define NBL        1024
#define FLAG_BYTES 256
#define WT_SHORTS  (512 * 128)
#define WT_BYTES   (WT_SHORTS * 2 * 2)   // hi+lo bf16
#define SLAB_U32   32768                 // 128 KB per (b,l)

__device__ __forceinline__ unsigned short f2bf(float x) {
    unsigned u = __builtin_bit_cast(unsigned, x);
    u += 0x7FFFu + ((u >> 16) & 1u);              // RNE
    return (unsigned short)(u >> 16);
}
__device__ __forceinline__ float bf2f(unsigned short b) {
    unsigned u = ((unsigned)b) << 16;
    return __builtin_bit_cast(float, u);
}

// split 8 consecutive f32 into bf16 hi/lo fragments (static indexing)
__device__ __forceinline__ void splitfrag(const float* __restrict__ ap,
                                          bf16x8& hi, bf16x8& lo) {
    float4 v0 = *(const float4*)ap;
    float4 v1 = *(const float4*)(ap + 4);
    unsigned short b;
    b = f2bf(v0.x); hi[0] = (short)b; lo[0] = (short)f2bf(v0.x - bf2f(b));
    b = f2bf(v0.y); hi[1] = (short)b; lo[1] = (short)f2bf(v0.y - bf2f(b));
    b = f2bf(v0.z); hi[2] = (short)b; lo[2] = (short)f2bf(v0.z - bf2f(b));
    b = f2bf(v0.w); hi[3] = (short)b; lo[3] = (short)f2bf(v0.w - bf2f(b));
    b = f2bf(v1.x); hi[4] = (short)b; lo[4] = (short)f2bf(v1.x - bf2f(b));
    b = f2bf(v1.y); hi[5] = (short)b; lo[5] = (short)f2bf(v1.y - bf2f(b));
    b = f2bf(v1.z); hi[6] = (short)b; lo[6] = (short)f2bf(v1.z - bf2f(b));
    b = f2bf(v1.w); hi[7] = (short)b; lo[7] = (short)f2bf(v1.w - bf2f(b));
}

// ------------------------------- Kd ----------------------------------------
__global__ void k_detect_mask(const unsigned int* __restrict__ m, int nwords,
                              int* __restrict__ flag) {
    __shared__ int f;
    if (threadIdx.x == 0) f = 0;
    __syncthreads();
    int acc = 0;
    for (int i = threadIdx.x; i < nwords; i += blockDim.x)
        acc |= (m[i] & ~1u) ? 1 : 0;
    if (acc) atomicOr(&f, 1);
    __syncthreads();
    if (threadIdx.x == 0) *flag = f;
}

// ------------------------------- K0 ----------------------------------------
__global__ void k0_prep_w(const float* __restrict__ W,
                          unsigned short* __restrict__ wt_hi,
                          unsigned short* __restrict__ wt_lo) {
    int g = blockIdx.x * 256 + threadIdx.x;        // 65536 elements
    int c = g >> 7, t = g & 127;
    float w = W[t * 512 + c] * 0.42044820762685725f;   // 32^-0.25
    unsigned short hb = f2bf(w);
    wt_hi[g] = hb;
    wt_lo[g] = f2bf(w - bf2f(hb));
}

// ------------------------------- KA ----------------------------------------
// grid = 1024; 512 threads = 8 waves (wm = j-half, wn = c-quarter).
// No LDS, no barriers. Slab u32 idx: Qsel(colk) + (colk&7)*2048 + j*16 + d0/2.
__launch_bounds__(512, 4)
__global__ void ka_gemm(const float* __restrict__ g2,
                        const unsigned short* __restrict__ wh,
                        const unsigned short* __restrict__ wl,
                        unsigned* __restrict__ slab) {
    const int tid  = threadIdx.x;
    const int lane = tid & 63;
    const int wv   = tid >> 6;
    const int colk = lane & 15;
    const int dgrp = lane >> 4;
    const int wm   = wv >> 2;          // 0..1 -> 64 j-rows
    const int wn   = wv & 3;           // 0..3 -> 32 c-cols
    const int bl   = blockIdx.x;

    const float* A = g2 + (size_t)bl * 16384;
    unsigned* sl   = slab + (size_t)bl * SLAB_U32;
    const unsigned hoff = ((colk & 8) ? 16384u : 0u) + (colk & 7) * 2048u;

#pragma unroll
    for (int nb = 0; nb < 4; ++nb) {
        f32x4 acc[4][2];
#pragma unroll
        for (int m = 0; m < 4; ++m)
#pragma unroll
            for (int n = 0; n < 2; ++n) acc[m][n] = (f32x4)0.0f;

#pragma unroll
        for (int kk = 0; kk < 4; ++kk) {
            const int t0 = kk * 32 + dgrp * 8;
            bf16x8 ah[4], al[4], bh[2], bl_[2];
#pragma unroll
            for (int m = 0; m < 4; ++m)
                splitfrag(A + (wm * 64 + m * 16 + colk) * 128 + t0, ah[m], al[m]);
#pragma unroll
            for (int n = 0; n < 2; ++n) {
                int c = nb * 128 + wn * 32 + n * 16 + colk;
                bh[n]  = *(const bf16x8*)(wh + c * 128 + t0);
                bl_[n] = *(const bf16x8*)(wl + c * 128 + t0);
            }
#pragma unroll
            for (int m = 0; m < 4; ++m)
#pragma unroll
                for (int n = 0; n < 2; ++n) {
                    acc[m][n] = __builtin_amdgcn_mfma_f32_16x16x32_bf16(ah[m], bh[n],  acc[m][n], 0, 0, 0);
                    acc[m][n] = __builtin_amdgcn_mfma_f32_16x16x32_bf16(ah[m], bl_[n], acc[m][n], 0, 0, 0);
                    acc[m][n] = __builtin_amdgcn_mfma_f32_16x16x32_bf16(al[m], bh[n],  acc[m][n], 0, 0, 0);
                }
        }
        const unsigned dHalf = (unsigned)(nb * 4 + wn);   // (d0=nb*8+wn*2)/2
#pragma unroll
        for (int m = 0; m < 4; ++m)
#pragma unroll
            for (int r = 0; r < 4; ++r) {
                int j = wm * 64 + m * 16 + dgrp * 4 + r;
                unsigned v = (unsigned)f2bf(acc[m][0][r]) |
                             ((unsigned)f2bf(acc[m][1][r]) << 16);
                sl[hoff + j * 16 + dHalf] = v;
            }
    }
}

// ------------------------------- KB ----------------------------------------
// grid = 1024; 512 threads = 8 waves; wave = head. q in 16-row chunks.
// LDS: S8[16][1153] f32 (73.8 KB) + tables (~3 KB) -> 2 WG/CU.
__launch_bounds__(512, 4)
__global__ void kb_attn(const unsigned short* __restrict__ slab16,
                        const float* __restrict__ h2,
                        const int* __restrict__ msk,
                        const float* __restrict__ sw,
                        const int* __restrict__ mask_is_bytes,
                        float* __restrict__ outp) {
    __shared__ float S8[16][1153];
    __shared__ float h2t[3][128];
    __shared__ float rowsw[128], colbias[128], colsw[128];

    const int tid  = threadIdx.x;
    const int lane = tid & 63;
    const int h    = tid >> 6;            // wave = head
    const int colk = lane & 15;
    const int dgrp = lane >> 4;
    const int bl   = blockIdx.x;

    if (tid < 128) {
        int  idx = bl * 128 + tid;
        bool mk  = (*mask_is_bytes)
                     ? (((const unsigned char*)msk)[idx] != 0)
                     : (msk[idx] != 0);
        float s  = sw[idx];
        rowsw[tid]   = mk ? s : 0.0f;
        colbias[tid] = mk ? 0.0f : -1e30f;
        colsw[tid]   = s;
    }
    if (tid < 384) {
        int c = tid >> 7, j = tid & 127;
        h2t[c][j] = h2[(size_t)bl * 384 + j * 3 + c];
    }

    // K fragments resident (coalesced 1 KB/wave reads from ws slab)
    const unsigned short* Qs = slab16 + (size_t)bl * 65536;
    const unsigned short* Ks = Qs + 32768;
    bf16x8 kf[8];
#pragma unroll
    for (int n = 0; n < 8; ++n)
        kf[n] = *(const bf16x8*)(Ks + h * 4096 + (n * 16 + colk) * 32 + dgrp * 8);

    __syncthreads();

    float cbias[8], cswr[8];
#pragma unroll
    for (int n = 0; n < 8; ++n) {
        int k = n * 16 + colk;
        cbias[n] = colbias[k];
        cswr[n]  = colsw[k];
    }

    for (int qc = 0; qc < 8; ++qc) {
        bf16x8 qf = *(const bf16x8*)(Qs + h * 4096 + (qc * 16 + colk) * 32 + dgrp * 8);

        f32x4 acc[8];
#pragma unroll
        for (int n = 0; n < 8; ++n) acc[n] = (f32x4)0.0f;
#pragma unroll
        for (int n = 0; n < 8; ++n)
            acc[n] = __builtin_amdgcn_mfma_f32_16x16x32_bf16(qf, kf[n], acc[n], 0, 0, 0);

        // masked softmax per q-row (rows qlocal = dgrp*4+r), scale, stage
#pragma unroll
        for (int r = 0; r < 4; ++r) {
            float mx = -1e30f;
#pragma unroll
            for (int n = 0; n < 8; ++n) mx = fmaxf(mx, acc[n][r] + cbias[n]);
#pragma unroll
            for (int off = 1; off < 16; off <<= 1) mx = fmaxf(mx, __shfl_xor(mx, off));
            float p[8], sum = 0.0f;
#pragma unroll
            for (int n = 0; n < 8; ++n) {
                p[n] = __expf(acc[n][r] + cbias[n] - mx);
                sum += p[n];
            }
#pragma unroll
            for (int off = 1; off < 16; off <<= 1) sum += __shfl_xor(sum, off);
            int   qlocal = dgrp * 4 + r;
            float scale  = rowsw[qc * 16 + qlocal] / sum;
#pragma unroll
            for (int n = 0; n < 8; ++n)
                S8[qlocal][(n * 16 + colk) * 9 + h] = p[n] * scale * cswr[n];
        }
        __syncthreads();

        // epilogue: h-contiguous 32B stores, * h2h2t[q][k]
        {
            int kx = (h & 1) * 64 + lane;
#pragma unroll
            for (int it = 0; it < 4; ++it) {
                int qlocal = (h >> 1) * 4 + it;
                int q = qc * 16 + qlocal;
                const float* srow = &S8[qlocal][kx * 9];
                float hh = (h2t[0][q] * h2t[0][kx] + h2t[1][q] * h2t[1][kx] +
                            h2t[2][q] * h2t[2][kx]) * 0.57735026918962576f;
                float4 o0 = {srow[0] * hh, srow[1] * hh, srow[2] * hh, srow[3] * hh};
                float4 o1 = {srow[4] * hh, srow[5] * hh, srow[6] * hh, srow[7] * hh};
                size_t ob = (((size_t)bl * 128 + q) * 128 + kx) * 8;
                *(float4*)(outp + ob)     = o0;
                *(float4*)(outp + ob + 4) = o1;
            }
        }
        __syncthreads();
    }
}

// ------------------------------- host --------------------------------------
extern "C" void kernel_launch(void* const* d_in, const int* in_sizes, int n_in,
                              void* d_out, int out_size, void* d_ws, size_t ws_size,
                              hipStream_t stream) {
    const float* g2  = (const float*)d_in[0];
    const float* h2  = (const float*)d_in[1];
    const int*   mk  = (const int*)d_in[2];
    const float* sw  = (const float*)d_in[3];
    const float* W   = (const float*)d_in[4];
    float*       out = (float*)d_out;
    char*        ws  = (char*)d_ws;

    int*            flag  = (int*)ws;
    unsigned short* wt_hi = (unsigned short*)(ws + FLAG_BYTES);
    unsigned short* wt_lo = wt_hi + WT_SHORTS;
    unsigned*       slab  = (unsigned*)(ws + FLAG_BYTES + WT_BYTES);

    int nwords = in_sizes[2] / 4;
    if (nwords > 8192) nwords = 8192;   // enough to distinguish, cheap
    k_detect_mask<<<dim3(1), dim3(256), 0, stream>>>(
        (const unsigned int*)mk, nwords, flag);
    k0_prep_w<<<dim3(256), dim3(256), 0, stream>>>(W, wt_hi, wt_lo);
    ka_gemm<<<dim3(NBL), dim3(512), 0, stream>>>(g2, wt_hi, wt_lo, slab);
    kb_attn<<<dim3(NBL), dim3(512), 0, stream>>>(
        (const unsigned short*)slab, h2, mk, sw, flag, out);
}

// Round 12
// 1043.832 us; speedup vs baseline: 1.3683x; 1.3683x over previous
//
#include <hip/hip_runtime.h>

// ---------------------------------------------------------------------------
// Atten2Map on MI355X (gfx950) — R10: fix ka register spills
// shapes: nb=4 nloc=256 nnei=128 ni=128, ND=32 NH=8, NBL=1024
//
// Kd : detect nlist_mask dtype (int32 vs byte-packed)      -> flag in ws
// K0 : Wt[c][t] = W[t][c] * 32^-0.25, split bf16 hi/lo     -> ws (512 KB)
// KA : per-(b,l) GEMM g2@Wt (split-bf16, 3-MFMA), NO LDS / NO barriers,
//      g2 split in-register; writes bf16 slab [Q/K][h][row][d] to ws.
// KB : per-(b,l) attn: K frags resident, q in 16-row chunks,
//      S8[16][1153] f32 (72 KB -> 2 WG/CU, conflict-free), epilogue
//      *h2h2t -> h-contiguous 32B stores to out[b,l,q,k,h].
//
// R9 post-mortem: ka with __launch_bounds__(512,4) (=128 unified regs) got
// VGPR_Count=64 + 64 AGPR and spilled fragments -> 1.87 GB scratch traffic
// per dispatch, 848 us (FETCH 584 MB, WRITE 1.25 GB vs ~70+134 expected).
// R10: ka -> (512,2) = 256 regs, no spill. kb untouched (never in top-5).
// R12: resubmit of R10 (rounds 10-11 lost to GPU acquisition timeouts).
// ---------------------------------------------------------------------------

typedef __attribute__((ext_vector_type(8))) short bf16x8;
typedef __attribute__((ext_vector_type(4))) float f32x4;

#define NBL        1024
#define FLAG_BYTES 256
#define WT_SHORTS  (512 * 128)
#define WT_BYTES   (WT_SHORTS * 2 * 2)   // hi+lo bf16
#define SLAB_U32   32768                 // 128 KB per (b,l)

__device__ __forceinline__ unsigned short f2bf(float x) {
    unsigned u = __builtin_bit_cast(unsigned, x);
    u += 0x7FFFu + ((u >> 16) & 1u);              // RNE
    return (unsigned short)(u >> 16);
}
__device__ __forceinline__ float bf2f(unsigned short b) {
    unsigned u = ((unsigned)b) << 16;
    return __builtin_bit_cast(float, u);
}

// split 8 consecutive f32 into bf16 hi/lo fragments (static indexing)
__device__ __forceinline__ void splitfrag(const float* __restrict__ ap,
                                          bf16x8& hi, bf16x8& lo) {
    float4 v0 = *(const float4*)ap;
    float4 v1 = *(const float4*)(ap + 4);
    unsigned short b;
    b = f2bf(v0.x); hi[0] = (short)b; lo[0] = (short)f2bf(v0.x - bf2f(b));
    b = f2bf(v0.y); hi[1] = (short)b; lo[1] = (short)f2bf(v0.y - bf2f(b));
    b = f2bf(v0.z); hi[2] = (short)b; lo[2] = (short)f2bf(v0.z - bf2f(b));
    b = f2bf(v0.w); hi[3] = (short)b; lo[3] = (short)f2bf(v0.w - bf2f(b));
    b = f2bf(v1.x); hi[4] = (short)b; lo[4] = (short)f2bf(v1.x - bf2f(b));
    b = f2bf(v1.y); hi[5] = (short)b; lo[5] = (short)f2bf(v1.y - bf2f(b));
    b = f2bf(v1.z); hi[6] = (short)b; lo[6] = (short)f2bf(v1.z - bf2f(b));
    b = f2bf(v1.w); hi[7] = (short)b; lo[7] = (short)f2bf(v1.w - bf2f(b));
}

// ------------------------------- Kd ----------------------------------------
__global__ void k_detect_mask(const unsigned int* __restrict__ m, int nwords,
                              int* __restrict__ flag) {
    __shared__ int f;
    if (threadIdx.x == 0) f = 0;
    __syncthreads();
    int acc = 0;
    for (int i = threadIdx.x; i < nwords; i += blockDim.x)
        acc |= (m[i] & ~1u) ? 1 : 0;
    if (acc) atomicOr(&f, 1);
    __syncthreads();
    if (threadIdx.x == 0) *flag = f;
}

// ------------------------------- K0 ----------------------------------------
__global__ void k0_prep_w(const float* __restrict__ W,
                          unsigned short* __restrict__ wt_hi,
                          unsigned short* __restrict__ wt_lo) {
    int g = blockIdx.x * 256 + threadIdx.x;        // 65536 elements
    int c = g >> 7, t = g & 127;
    float w = W[t * 512 + c] * 0.42044820762685725f;   // 32^-0.25
    unsigned short hb = f2bf(w);
    wt_hi[g] = hb;
    wt_lo[g] = f2bf(w - bf2f(hb));
}

// ------------------------------- KA ----------------------------------------
// grid = 1024; 512 threads = 8 waves (wm = j-half, wn = c-quarter).
// No LDS, no barriers. Slab u32 idx: Qsel(colk) + (colk&7)*2048 + j*16 + d0/2.
// (512,2): 256 unified VGPR+AGPR per wave -> ~144 live regs fit, NO spill.
__launch_bounds__(512, 2)
__global__ void ka_gemm(const float* __restrict__ g2,
                        const unsigned short* __restrict__ wh,
                        const unsigned short* __restrict__ wl,
                        unsigned* __restrict__ slab) {
    const int tid  = threadIdx.x;
    const int lane = tid & 63;
    const int wv   = tid >> 6;
    const int colk = lane & 15;
    const int dgrp = lane >> 4;
    const int wm   = wv >> 2;          // 0..1 -> 64 j-rows
    const int wn   = wv & 3;           // 0..3 -> 32 c-cols
    const int bl   = blockIdx.x;

    const float* A = g2 + (size_t)bl * 16384;
    unsigned* sl   = slab + (size_t)bl * SLAB_U32;
    const unsigned hoff = ((colk & 8) ? 16384u : 0u) + (colk & 7) * 2048u;

#pragma unroll
    for (int nb = 0; nb < 4; ++nb) {
        f32x4 acc[4][2];
#pragma unroll
        for (int m = 0; m < 4; ++m)
#pragma unroll
            for (int n = 0; n < 2; ++n) acc[m][n] = (f32x4)0.0f;

#pragma unroll
        for (int kk = 0; kk < 4; ++kk) {
            const int t0 = kk * 32 + dgrp * 8;
            bf16x8 ah[4], al[4], bh[2], bl_[2];
#pragma unroll
            for (int m = 0; m < 4; ++m)
                splitfrag(A + (wm * 64 + m * 16 + colk) * 128 + t0, ah[m], al[m]);
#pragma unroll
            for (int n = 0; n < 2; ++n) {
                int c = nb * 128 + wn * 32 + n * 16 + colk;
                bh[n]  = *(const bf16x8*)(wh + c * 128 + t0);
                bl_[n] = *(const bf16x8*)(wl + c * 128 + t0);
            }
#pragma unroll
            for (int m = 0; m < 4; ++m)
#pragma unroll
                for (int n = 0; n < 2; ++n) {
                    acc[m][n] = __builtin_amdgcn_mfma_f32_16x16x32_bf16(ah[m], bh[n],  acc[m][n], 0, 0, 0);
                    acc[m][n] = __builtin_amdgcn_mfma_f32_16x16x32_bf16(ah[m], bl_[n], acc[m][n], 0, 0, 0);
                    acc[m][n] = __builtin_amdgcn_mfma_f32_16x16x32_bf16(al[m], bh[n],  acc[m][n], 0, 0, 0);
                }
        }
        const unsigned dHalf = (unsigned)(nb * 4 + wn);   // (d0=nb*8+wn*2)/2
#pragma unroll
        for (int m = 0; m < 4; ++m)
#pragma unroll
            for (int r = 0; r < 4; ++r) {
                int j = wm * 64 + m * 16 + dgrp * 4 + r;
                unsigned v = (unsigned)f2bf(acc[m][0][r]) |
                             ((unsigned)f2bf(acc[m][1][r]) << 16);
                sl[hoff + j * 16 + dHalf] = v;
            }
    }
}

// ------------------------------- KB ----------------------------------------
// grid = 1024; 512 threads = 8 waves; wave = head. q in 16-row chunks.
// LDS: S8[16][1153] f32 (73.8 KB) + tables (~3 KB) -> 2 WG/CU.
// ~104 live regs (32 AGPR acc + ~72 VGPR) fits the (512,4) 128-reg budget.
__launch_bounds__(512, 4)
__global__ void kb_attn(const unsigned short* __restrict__ slab16,
                        const float* __restrict__ h2,
                        const int* __restrict__ msk,
                        const float* __restrict__ sw,
                        const int* __restrict__ mask_is_bytes,
                        float* __restrict__ outp) {
    __shared__ float S8[16][1153];
    __shared__ float h2t[3][128];
    __shared__ float rowsw[128], colbias[128], colsw[128];

    const int tid  = threadIdx.x;
    const int lane = tid & 63;
    const int h    = tid >> 6;            // wave = head
    const int colk = lane & 15;
    const int dgrp = lane >> 4;
    const int bl   = blockIdx.x;

    if (tid < 128) {
        int  idx = bl * 128 + tid;
        bool mk  = (*mask_is_bytes)
                     ? (((const unsigned char*)msk)[idx] != 0)
                     : (msk[idx] != 0);
        float s  = sw[idx];
        rowsw[tid]   = mk ? s : 0.0f;
        colbias[tid] = mk ? 0.0f : -1e30f;
        colsw[tid]   = s;
    }
    if (tid < 384) {
        int c = tid >> 7, j = tid & 127;
        h2t[c][j] = h2[(size_t)bl * 384 + j * 3 + c];
    }

    // K fragments resident (wave covers contiguous 1 KB per load)
    const unsigned short* Qs = slab16 + (size_t)bl * 65536;
    const unsigned short* Ks = Qs + 32768;
    bf16x8 kf[8];
#pragma unroll
    for (int n = 0; n < 8; ++n)
        kf[n] = *(const bf16x8*)(Ks + h * 4096 + (n * 16 + colk) * 32 + dgrp * 8);

    __syncthreads();

    float cbias[8], cswr[8];
#pragma unroll
    for (int n = 0; n < 8; ++n) {
        int k = n * 16 + colk;
        cbias[n] = colbias[k];
        cswr[n]  = colsw[k];
    }

    for (int qc = 0; qc < 8; ++qc) {
        bf16x8 qf = *(const bf16x8*)(Qs + h * 4096 + (qc * 16 + colk) * 32 + dgrp * 8);

        f32x4 acc[8];
#pragma unroll
        for (int n = 0; n < 8; ++n) acc[n] = (f32x4)0.0f;
#pragma unroll
        for (int n = 0; n < 8; ++n)
            acc[n] = __builtin_amdgcn_mfma_f32_16x16x32_bf16(qf, kf[n], acc[n], 0, 0, 0);

        // masked softmax per q-row (rows qlocal = dgrp*4+r), scale, stage
#pragma unroll
        for (int r = 0; r < 4; ++r) {
            float mx = -1e30f;
#pragma unroll
            for (int n = 0; n < 8; ++n) mx = fmaxf(mx, acc[n][r] + cbias[n]);
#pragma unroll
            for (int off = 1; off < 16; off <<= 1) mx = fmaxf(mx, __shfl_xor(mx, off));
            float p[8], sum = 0.0f;
#pragma unroll
            for (int n = 0; n < 8; ++n) {
                p[n] = __expf(acc[n][r] + cbias[n] - mx);
                sum += p[n];
            }
#pragma unroll
            for (int off = 1; off < 16; off <<= 1) sum += __shfl_xor(sum, off);
            int   qlocal = dgrp * 4 + r;
            float scale  = rowsw[qc * 16 + qlocal] / sum;
#pragma unroll
            for (int n = 0; n < 8; ++n)
                S8[qlocal][(n * 16 + colk) * 9 + h] = p[n] * scale * cswr[n];
        }
        __syncthreads();

        // epilogue: h-contiguous 32B stores, * h2h2t[q][k]
        {
            int kx = (h & 1) * 64 + lane;
#pragma unroll
            for (int it = 0; it < 4; ++it) {
                int qlocal = (h >> 1) * 4 + it;
                int q = qc * 16 + qlocal;
                const float* srow = &S8[qlocal][kx * 9];
                float hh = (h2t[0][q] * h2t[0][kx] + h2t[1][q] * h2t[1][kx] +
                            h2t[2][q] * h2t[2][kx]) * 0.57735026918962576f;
                float4 o0 = {srow[0] * hh, srow[1] * hh, srow[2] * hh, srow[3] * hh};
                float4 o1 = {srow[4] * hh, srow[5] * hh, srow[6] * hh, srow[7] * hh};
                size_t ob = (((size_t)bl * 128 + q) * 128 + kx) * 8;
                *(float4*)(outp + ob)     = o0;
                *(float4*)(outp + ob + 4) = o1;
            }
        }
        __syncthreads();
    }
}

// ------------------------------- host --------------------------------------
extern "C" void kernel_launch(void* const* d_in, const int* in_sizes, int n_in,
                              void* d_out, int out_size, void* d_ws, size_t ws_size,
                              hipStream_t stream) {
    const float* g2  = (const float*)d_in[0];
    const float* h2  = (const float*)d_in[1];
    const int*   mk  = (const int*)d_in[2];
    const float* sw  = (const float*)d_in[3];
    const float* W   = (const float*)d_in[4];
    float*       out = (float*)d_out;
    char*        ws  = (char*)d_ws;

    int*            flag  = (int*)ws;
    unsigned short* wt_hi = (unsigned short*)(ws + FLAG_BYTES);
    unsigned short* wt_lo = wt_hi + WT_SHORTS;
    unsigned*       slab  = (unsigned*)(ws + FLAG_BYTES + WT_BYTES);

    int nwords = in_sizes[2] / 4;
    if (nwords > 8192) nwords = 8192;   // enough to distinguish, cheap
    k_detect_mask<<<dim3(1), dim3(256), 0, stream>>>(
        (const unsigned int*)mk, nwords, flag);
    k0_prep_w<<<dim3(256), dim3(256), 0, stream>>>(W, wt_hi, wt_lo);
    ka_gemm<<<dim3(NBL), dim3(512), 0, stream>>>(g2, wt_hi, wt_lo, slab);
    kb_attn<<<dim3(NBL), dim3(512), 0, stream>>>(
        (const unsigned short*)slab, h2, mk, sw, flag, out);
}